// Round 8
// baseline (23.343 us; speedup 1.0000x reference)
//
#include <hip/hip_runtime.h>
#include <math.h>

#define Bc 4
#define Cc 128
#define Pc 64
#define PLANE 576      // 24*24
#define VOL   13824    // 24^3
#define NI    (-INFINITY)

// One wave per (proposal, 4 channels {c, c+32, c+64, c+96}). Bounds/biases/
// loop control amortized over 4 channel streams; 4-8 independent loads in
// flight per step. w-biases are SHARED across row-chunks (row validity is
// folded into the per-chunk h-masks instead; invalid rows accumulate real
// data that the merge discards). d-region split = 3 uniform scalar segments
// (region0 / overlap / region1), x2 unrolled. Epilogue: select-exchange
// octant reduce per channel; lanes 0..31 store one float (coalesced).

struct Acc { float v00, v01, v10, v11; };   // [d-region][w-region]

template<int RMODE>   // 0: d-region0, 1: d-region1, 2: both (overlap plane)
__device__ __forceinline__ void upd(Acc& a, float t0, float t1) {
    if (RMODE != 1) { a.v00 = fmaxf(a.v00, t0); a.v01 = fmaxf(a.v01, t1); }
    if (RMODE != 0) { a.v10 = fmaxf(a.v10, t0); a.v11 = fmaxf(a.v11, t1); }
}

template<int RMODE>
__device__ __forceinline__ void plane_chunk(
    const float* __restrict__ p0, const float* __restrict__ p1,
    const float* __restrict__ p2, const float* __restrict__ p3,
    int fcl, const float4& B0, const float4& B1,
    Acc& a0, Acc& a1, Acc& a2, Acc& a3)
{
    float4 v0 = *(const float4*)(p0 + fcl);
    float4 v1 = *(const float4*)(p1 + fcl);
    float4 v2 = *(const float4*)(p2 + fcl);
    float4 v3 = *(const float4*)(p3 + fcl);
#define TREE(v, B) fmaxf(fmaxf((v).x + (B).x, (v).y + (B).y),              \
                         fmaxf((v).z + (B).z, (v).w + (B).w))
    upd<RMODE>(a0, TREE(v0, B0), TREE(v0, B1));
    upd<RMODE>(a1, TREE(v1, B0), TREE(v1, B1));
    upd<RMODE>(a2, TREE(v2, B0), TREE(v2, B1));
    upd<RMODE>(a3, TREE(v3, B0), TREE(v3, B1));
#undef TREE
}

// o[j] = candidate max for octant j (j = dr*4 + hr*2 + wr) on this lane.
__device__ __forceinline__ float oct_reduce(const float o[8], int lane) {
    const bool b0 = lane & 1, b1 = lane & 2, b2 = lane & 4;
    float m0 = fmaxf(b0 ? o[1] : o[0], __shfl_xor(b0 ? o[0] : o[1], 1));
    float m1 = fmaxf(b0 ? o[3] : o[2], __shfl_xor(b0 ? o[2] : o[3], 1));
    float m2 = fmaxf(b0 ? o[5] : o[4], __shfl_xor(b0 ? o[4] : o[5], 1));
    float m3 = fmaxf(b0 ? o[7] : o[6], __shfl_xor(b0 ? o[6] : o[7], 1));
    float n0 = fmaxf(b1 ? m1 : m0, __shfl_xor(b1 ? m0 : m1, 2));
    float n1 = fmaxf(b1 ? m3 : m2, __shfl_xor(b1 ? m2 : m3, 2));
    float v  = fmaxf(b2 ? n1 : n0, __shfl_xor(b2 ? n0 : n1, 4));
    v = fmaxf(v, __shfl_xor(v, 8));
    v = fmaxf(v, __shfl_xor(v, 16));
    v = fmaxf(v, __shfl_xor(v, 32));
    return v;
}

__global__ __launch_bounds__(256) void crop_pool_kernel(
    const float* __restrict__ fm, const int* __restrict__ corners,
    const int* __restrict__ scale_p, float* __restrict__ out)
{
    const int lane = threadIdx.x & 63;
    const int wid  = threadIdx.x >> 6;   // 0..3
    const int bp   = blockIdx.x >> 3;    // 8 consecutive blocks per proposal
    const int cg   = blockIdx.x & 7;
    const int slot = cg * 4 + wid;       // 0..31
    const int b    = bp >> 6;            // P = 64

    const float inv = 1.0f / (float)scale_p[0];   // uniform; exact-floor mul

    // Per-axis bounds (k: 0->D, 1->H, 2->W), uniform -> SGPR.
    int s[3], e[3], m0a[3], m1a[3];
#pragma unroll
    for (int k = 0; k < 3; ++k) {
        int c0 = corners[(bp * 2 + 0) * 3 + k];
        int c1 = corners[(bp * 2 + 1) * 3 + k];
        int p1v = (int)((float)c0 * inv);     // == c0/scale (c0 in [0,95])
        p1v = p1v > 21 ? 21 : p1v;
        int p2v = (int)((float)c1 * inv);
        if (p2v - p1v < 2) p2v = p1v + 2;
        int ee = p2v < 24 ? p2v : 24;
        int n  = ee - p1v;                    // 2..23
        s[k]   = __builtin_amdgcn_readfirstlane(p1v);
        e[k]   = __builtin_amdgcn_readfirstlane(ee);
        m0a[k] = __builtin_amdgcn_readfirstlane(p1v + ((n + 1) >> 1)); // r0 end
        m1a[k] = __builtin_amdgcn_readfirstlane(p1v + (n >> 1));       // r1 start
    }

    const int sh  = s[1], eh = e[1], nh = eh - sh;
    const int m0h = m0a[1], m1h = m1a[1];
    const int sw  = s[2], ew = e[2], m0w = m0a[2], m1w = m1a[2];

    const int qb = sw & ~3;                            // aligned w base
    const int Q  = ((sw & 3) + (ew - sw) + 3) >> 2;    // quads per row, 1..7
    const int R  = 64 / Q;                             // rows per sweep, >= 9

    // lane/Q via exact magic multiply (Q<=7, lane<=63)
    const unsigned M = (65536u + (unsigned)Q - 1) / (unsigned)Q;
    const int r = (int)(((unsigned)lane * M) >> 16);
    const int q = lane - r * Q;
    const int wbase = qb + 4 * q;                      // 4-aligned, <= 20

    const bool c1p = nh > R;                 // wave-uniform chunk presence
    const bool c2p = nh > 2 * R;

    // Shared w-biases (validity NOT folded; that lives in the h-masks)
    float4 B0, B1;
    {
        int wt;
        wt = wbase + 0;
        B0.x = (wt >= sw  && wt < m0w) ? 0.0f : NI;
        B1.x = (wt >= m1w && wt < ew ) ? 0.0f : NI;
        wt = wbase + 1;
        B0.y = (wt >= sw  && wt < m0w) ? 0.0f : NI;
        B1.y = (wt >= m1w && wt < ew ) ? 0.0f : NI;
        wt = wbase + 2;
        B0.z = (wt >= sw  && wt < m0w) ? 0.0f : NI;
        B1.z = (wt >= m1w && wt < ew ) ? 0.0f : NI;
        wt = wbase + 3;
        B0.w = (wt >= sw  && wt < m0w) ? 0.0f : NI;
        B1.w = (wt >= m1w && wt < ew ) ? 0.0f : NI;
    }

    // Per-chunk row state: clamped offset + h-masks (validity folded in)
    int  fcl[3];
    bool h0m[3], h1m[3];
#pragma unroll
    for (int K = 0; K < 3; ++K) {
        const int h  = sh + K * R + r;
        const bool va = h < eh;                 // hrow < nh
        const int  f  = h * 24 + wbase;
        fcl[K] = f < (PLANE - 4) ? f : (PLANE - 4);
        h0m[K] = va && (h <  m0h);
        h1m[K] = va && (h >= m1h);
    }

    Acc A[4][3];
#pragma unroll
    for (int i = 0; i < 4; ++i)
#pragma unroll
        for (int K = 0; K < 3; ++K) { A[i][K].v00=NI; A[i][K].v01=NI;
                                      A[i][K].v10=NI; A[i][K].v11=NI; }

    const float* pA = fm + ((size_t)(b * Cc + slot     )) * VOL + (size_t)s[0] * PLANE;
    const float* pB = fm + ((size_t)(b * Cc + slot + 32)) * VOL + (size_t)s[0] * PLANE;
    const float* pC = fm + ((size_t)(b * Cc + slot + 64)) * VOL + (size_t)s[0] * PLANE;
    const float* pD = fm + ((size_t)(b * Cc + slot + 96)) * VOL + (size_t)s[0] * PLANE;

#define STEP_AT(RM, OFF)                                                    \
    {                                                                       \
        plane_chunk<RM>(pA+(OFF), pB+(OFF), pC+(OFF), pD+(OFF), fcl[0],     \
                        B0, B1, A[0][0], A[1][0], A[2][0], A[3][0]);        \
        if (c1p) plane_chunk<RM>(pA+(OFF), pB+(OFF), pC+(OFF), pD+(OFF),    \
                        fcl[1], B0, B1, A[0][1], A[1][1], A[2][1], A[3][1]);\
        if (c2p) plane_chunk<RM>(pA+(OFF), pB+(OFF), pC+(OFF), pD+(OFF),    \
                        fcl[2], B0, B1, A[0][2], A[1][2], A[2][2], A[3][2]);\
    }
#define ADV(NP) { pA += (NP)*PLANE; pB += (NP)*PLANE; pC += (NP)*PLANE; pD += (NP)*PLANE; }

    int d = s[0];
    for (; d + 2 <= m1a[0]; d += 2) { STEP_AT(0, 0) STEP_AT(0, PLANE) ADV(2) }
    for (; d < m1a[0]; ++d)         { STEP_AT(0, 0) ADV(1) }
    for (; d < m0a[0]; ++d)         { STEP_AT(2, 0) ADV(1) }   // overlap plane
    for (; d + 2 <= e[0]; d += 2)   { STEP_AT(1, 0) STEP_AT(1, PLANE) ADV(2) }
    for (; d < e[0]; ++d)           { STEP_AT(1, 0) ADV(1) }
#undef ADV
#undef STEP_AT

    // Merge chunks with per-chunk h-masks into 8 octants, reduce, store.
    float vch[4];
#pragma unroll
    for (int i = 0; i < 4; ++i) {
        float o[8];
#pragma unroll
        for (int j = 0; j < 8; ++j) o[j] = NI;
#pragma unroll
        for (int K = 0; K < 3; ++K) {
            if (K == 1 && !c1p) continue;
            if (K == 2 && !c2p) continue;
            o[0] = fmaxf(o[0], h0m[K] ? A[i][K].v00 : NI);
            o[1] = fmaxf(o[1], h0m[K] ? A[i][K].v01 : NI);
            o[2] = fmaxf(o[2], h1m[K] ? A[i][K].v00 : NI);
            o[3] = fmaxf(o[3], h1m[K] ? A[i][K].v01 : NI);
            o[4] = fmaxf(o[4], h0m[K] ? A[i][K].v10 : NI);
            o[5] = fmaxf(o[5], h0m[K] ? A[i][K].v11 : NI);
            o[6] = fmaxf(o[6], h1m[K] ? A[i][K].v10 : NI);
            o[7] = fmaxf(o[7], h1m[K] ? A[i][K].v11 : NI);
        }
        vch[i] = oct_reduce(o, lane);
    }

    if (lane < 32) {
        const float vv = (lane & 16) ? ((lane & 8) ? vch[3] : vch[2])
                                     : ((lane & 8) ? vch[1] : vch[0]);
        const int   cc = slot + 32 * (lane >> 3);
        out[((size_t)bp * Cc + cc) * 8 + (lane & 7)] = vv;
    }
}

extern "C" void kernel_launch(void* const* d_in, const int* in_sizes, int n_in,
                              void* d_out, int out_size, void* d_ws, size_t ws_size,
                              hipStream_t stream) {
    const float* fm      = (const float*)d_in[0];
    const int*   corners = (const int*)d_in[1];
    const int*   scale   = (const int*)d_in[2];
    float*       out     = (float*)d_out;

    dim3 grid(Bc * Pc * 8);    // 2048 blocks: one wave per (proposal, 4 ch)
    dim3 block(256);
    crop_pool_kernel<<<grid, block, 0, stream>>>(fm, corners, scale, out);
}